// Round 8
// baseline (268.036 us; speedup 1.0000x reference)
//
#include <hip/hip_runtime.h>
#include <hip/hip_bf16.h>
#include <stdint.h>

// MoTEmbed: out[t,:] = W_{type(t)} @ h[t,:] + b_{type(t)}
// B=4, S=4096 -> T=16384 tokens, D=2048. fp32 in/out, bf16 MFMA compute.
// Round 8: barrier-minimal K-loop (2 barriers/tile instead of 8, counted
// vmcnt(8), stage-at-tile-end, compiler-scheduled ds_read<->MFMA overlap).
// Swizzle/staging/fragment maps byte-identical to the verified round-7.

#define T_TOK 16384
#define DDIM  2048
#define NT_K  32           // K tiles of 64
#define MT    65           // M tiles of 256 (64 + 1 pad-split)
#define NTILE 8            // N tiles of 256

typedef __attribute__((ext_vector_type(4))) float          f32x4;
typedef __attribute__((ext_vector_type(8))) short          bf16x8;
typedef __attribute__((ext_vector_type(2))) unsigned int   u32x2;

// ---- ws layout (bytes) ----
#define WS_HBF   0ull
#define WS_W0BF  67108864ull                 // 16384*2048*2
#define WS_W1BF  75497472ull                 // + 2048*2048*2
#define WS_META  83886080ull                 // + 2048*2048*2
#define WS_IDX   83886208ull
#define WS_NEED  (WS_IDX + (unsigned long long)(T_TOK + 256) * 4ull)
// meta: [0]=c0 [1]=unused [2]=cur0 [3]=cur1

__device__ __forceinline__ unsigned short cvt1_bf16(float f) {
  unsigned u = __builtin_bit_cast(unsigned, f);
  unsigned rnd = 0x7fffu + ((u >> 16) & 1u);
  return (unsigned short)((u + rnd) >> 16);
}

__device__ __forceinline__ void gload_lds16(const void* g, void* l) {
  __builtin_amdgcn_global_load_lds(
      (const __attribute__((address_space(1))) unsigned int*)g,
      (__attribute__((address_space(3))) unsigned int*)l, 16, 0, 0);
}

#define BAR()    asm volatile("s_barrier" ::: "memory")
#define VMCNT8() asm volatile("s_waitcnt vmcnt(8)" ::: "memory")

// ---------- prep kernels ----------
__global__ void k_convert(const float* __restrict__ src,
                          unsigned short* __restrict__ dst, int n4) {
  int i = blockIdx.x * blockDim.x + threadIdx.x;
  int stride = gridDim.x * blockDim.x;
  for (; i < n4; i += stride) {
    f32x4 v = ((const f32x4*)src)[i];
    unsigned p0 = (unsigned)cvt1_bf16(v[0]) | ((unsigned)cvt1_bf16(v[1]) << 16);
    unsigned p1 = (unsigned)cvt1_bf16(v[2]) | ((unsigned)cvt1_bf16(v[3]) << 16);
    u32x2 o; o[0] = p0; o[1] = p1;
    ((u32x2*)dst)[i] = o;
  }
}

__global__ void k_init(int* __restrict__ meta, int* __restrict__ idx, int n) {
  int i = blockIdx.x * blockDim.x + threadIdx.x;
  if (i < 4) meta[i] = 0;
  if (i < n) idx[i] = -1;
}

__global__ void k_count(const int* __restrict__ typ, int* __restrict__ meta) {
  int i = blockIdx.x * blockDim.x + threadIdx.x;
  if (i < T_TOK && typ[i] == 0) atomicAdd(&meta[0], 1);
}

__global__ void k_scatter(const int* __restrict__ typ, int* __restrict__ meta,
                          int* __restrict__ idx) {
  int i = blockIdx.x * blockDim.x + threadIdx.x;
  if (i >= T_TOK) return;
  int pad = ((meta[0] + 255) >> 8) << 8;   // meta[0] final (prior kernel)
  int t = typ[i];
  int pos;
  if (t == 0) pos = atomicAdd(&meta[2], 1);
  else        pos = pad + atomicAdd(&meta[3], 1);
  idx[pos] = i;
}

// ---------- 256x256 GEMM, barrier-minimal pipeline ----------
// LDS: A[2 buf][2 kh][256 rows][64 B] = 64KB, then B same = 64KB.
// Swizzle (verified R7, conflicts == 0): data (row, slot s) at slot
// s ^ ((row>>1)&3); write via pre-swizzled global source slot
// cs = (lane&3) ^ ((lane>>3)&3); read slot = g ^ ((fr>>1)&3).
// Pipeline: S_k = 8 loads staging tile k. Prologue: S0, S1. Tile t entry:
// outstanding {S_t, S_t+1} = 16 -> vmcnt(8) drains S_t; BAR -> cross-wave
// visible; body reads buf(t&1) + 64 MFMA (compiler-scheduled lgkmcnt);
// BAR certifies reads done; stage S_t+2 into buf(t&1). Never vmcnt(0).
__global__ __launch_bounds__(512, 2) void k_gemm256(
    const unsigned short* __restrict__ Hbf,
    const unsigned short* __restrict__ W0bf,
    const unsigned short* __restrict__ W1bf,
    const float* __restrict__ B0, const float* __restrict__ B1,
    const int* __restrict__ meta, const int* __restrict__ idx,
    float* __restrict__ OUT)
{
  __shared__ char lds[131072];

  // bijective XCD swizzle: nwg=520, 520%8==0, chunk=65
  const int orig = blockIdx.x;
  const int wg = (orig & 7) * 65 + (orig >> 3);
  const int my = wg >> 3;              // 0..64
  const int bx = wg & 7;               // 0..7

  const int tid  = threadIdx.x;
  const int lane = tid & 63;
  const int wid  = tid >> 6;           // 0..7
  const int wr   = wid >> 2;           // 0..1 (M half)
  const int wc   = wid & 3;            // 0..3 (N quarter)
  const int fr   = lane & 15;
  const int g    = lane >> 4;

  const int start  = my * 256;
  const int c0pad  = ((meta[0] + 255) >> 8) << 8;
  const int expert = (start >= c0pad) ? 1 : 0;
  const unsigned short* Wb = expert ? W1bf : W0bf;
  const int colBase = bx * 256;

  // staging sources; pre-swizzled global slot (linear LDS dest)
  const int cs = (lane & 3) ^ ((lane >> 3) & 3);
  const char* aS[2];
  const char* wS[2];
#pragma unroll
  for (int l = 0; l < 2; ++l) {
    int ch = 2 * wid + l;
    int r_tile = ch * 16 + (lane >> 2);
    int orow = idx[start + r_tile];
    if (orow < 0) orow = 0;
    aS[l] = (const char*)Hbf + (size_t)orow * 4096 + cs * 16;
    wS[l] = (const char*)(Wb + (size_t)(colBase + r_tile) * DDIM) + cs * 16;
  }
  const int chB = (2 * wid) * 1024;    // wave-uniform chunk base in a section

  // fragment byte offsets within a kh-section (swizzled slot)
  const int sw = (g ^ ((fr >> 1) & 3)) << 4;
  int aF[8], bF[4];
#pragma unroll
  for (int m = 0; m < 8; ++m) aF[m] = ((wr * 128 + m * 16 + fr) << 6) + sw;
#pragma unroll
  for (int n = 0; n < 4; ++n) bF[n] = ((wc * 64 + n * 16 + fr) << 6) + sw;

  f32x4 acc[8][4];
#pragma unroll
  for (int m = 0; m < 8; ++m)
#pragma unroll
    for (int n = 0; n < 4; ++n) acc[m][n] = (f32x4)0.0f;

  // stage tile tn into buffer d: 8 loads/thread (A kh0, A kh1, B kh0, B kh1)
  auto STAGE_T = [&](int d, int tn) {
    int ko0 = tn * 128;
    int ko1 = tn * 128 + 64;
    char* ad = lds + (d << 15) + chB;
    char* wd = lds + 65536 + (d << 15) + chB;
    gload_lds16(aS[0] + ko0, ad);
    gload_lds16(aS[1] + ko0, ad + 1024);
    gload_lds16(aS[0] + ko1, ad + 16384);
    gload_lds16(aS[1] + ko1, ad + 16384 + 1024);
    gload_lds16(wS[0] + ko0, wd);
    gload_lds16(wS[1] + ko0, wd + 1024);
    gload_lds16(wS[0] + ko1, wd + 16384);
    gload_lds16(wS[1] + ko1, wd + 16384 + 1024);
  };

  // prologue: tiles 0,1 into bufs 0,1
  STAGE_T(0, 0);
  STAGE_T(1, 1);

#pragma unroll 2
  for (int t = 0; t < NT_K; ++t) {
    const int c = t & 1;
    VMCNT8();                          // drain S_t (leaves S_t+1 in flight)
    BAR();                             // cross-wave: buf c fully visible
    const char* Ak0 = lds + (c << 15);
    const char* Ak1 = Ak0 + 16384;
    const char* Bk0 = lds + 65536 + (c << 15);
    const char* Bk1 = Bk0 + 16384;

    // kh0
    {
      bf16x8 a[8], b[4];
#pragma unroll
      for (int m = 0; m < 8; ++m) a[m] = *(const bf16x8*)(Ak0 + aF[m]);
#pragma unroll
      for (int n = 0; n < 4; ++n) b[n] = *(const bf16x8*)(Bk0 + bF[n]);
      __builtin_amdgcn_s_setprio(1);
#pragma unroll
      for (int n = 0; n < 4; ++n)
#pragma unroll
        for (int m = 0; m < 8; ++m)
          acc[m][n] = __builtin_amdgcn_mfma_f32_16x16x32_bf16(a[m], b[n], acc[m][n], 0, 0, 0);
      __builtin_amdgcn_s_setprio(0);
    }
    // kh1
    {
      bf16x8 a[8], b[4];
#pragma unroll
      for (int m = 0; m < 8; ++m) a[m] = *(const bf16x8*)(Ak1 + aF[m]);
#pragma unroll
      for (int n = 0; n < 4; ++n) b[n] = *(const bf16x8*)(Bk1 + bF[n]);
      __builtin_amdgcn_s_setprio(1);
#pragma unroll
      for (int n = 0; n < 4; ++n)
#pragma unroll
        for (int m = 0; m < 8; ++m)
          acc[m][n] = __builtin_amdgcn_mfma_f32_16x16x32_bf16(a[m], b[n], acc[m][n], 0, 0, 0);
      __builtin_amdgcn_s_setprio(0);
    }

    BAR();                             // all waves done reading buf c
    int tn = t + 2; if (tn >= NT_K) tn = NT_K - 1;  // clamp keeps census = 8/tile
    STAGE_T(c, tn);                    // overwrite just-read buffer
  }

  // ---- epilogue: bias + scatter to original rows ----
  const float* Bv = expert ? B1 : B0;
  float bias[4];
  int cols[4];
#pragma unroll
  for (int n = 0; n < 4; ++n) {
    cols[n] = colBase + wc * 64 + n * 16 + fr;
    bias[n] = Bv[cols[n]];
  }
#pragma unroll
  for (int m = 0; m < 8; ++m) {
    int lb = wr * 128 + m * 16 + (g << 2);
#pragma unroll
    for (int j = 0; j < 4; ++j) {
      int orow = idx[start + lb + j];
      if (orow < 0) continue;
      float* op = OUT + (size_t)orow * DDIM;
#pragma unroll
      for (int n = 0; n < 4; ++n) op[cols[n]] = acc[m][n][j] + bias[n];
    }
  }
}

// ---------- fallback: verified round-4 kernel ----------
#define BMd 64
#define BNd 64
#define BKd 32
#define LDW 36

__device__ __forceinline__ bf16x8 cvt_bf16x8(f32x4 lo, f32x4 hi) {
  bf16x8 r;
#pragma unroll
  for (int i = 0; i < 4; ++i) {
    r[i]     = (short)cvt1_bf16(lo[i]);
    r[i + 4] = (short)cvt1_bf16(hi[i]);
  }
  return r;
}

__global__ __launch_bounds__(256, 2) void mot_mfma_diag(
    const float* __restrict__ H,  const int* __restrict__ TYP,
    const float* __restrict__ W0, const float* __restrict__ B0,
    const float* __restrict__ W1, const float* __restrict__ B1,
    float* __restrict__ OUT)
{
  __shared__ float As[BMd * LDW];
  __shared__ float W0s[BNd * LDW];
  __shared__ float W1s[BNd * LDW];

  const int tid = threadIdx.x;
  const int rowBase = blockIdx.y * BMd;
  const int colBase = blockIdx.x * BNd;
  const int srow  = tid >> 3;
  const int scol4 = (tid & 7) << 2;
  const float* hA  = H  + (size_t)(rowBase + srow) * DDIM + scol4;
  const float* hW0 = W0 + (size_t)(colBase + srow) * DDIM + scol4;
  const float* hW1 = W1 + (size_t)(colBase + srow) * DDIM + scol4;

  const int lane = tid & 63;
  const int w    = tid >> 6;
  const int fr   = lane & 15;
  const int g    = lane >> 4;

  f32x4 acc0[4], acc1[4];
#pragma unroll
  for (int m = 0; m < 4; ++m) { acc0[m] = (f32x4)0.0f; acc1[m] = (f32x4)0.0f; }

  for (int k0 = 0; k0 < DDIM; k0 += BKd) {
    f32x4 va[2], v0[2], v1[2];
#pragma unroll
    for (int p = 0; p < 2; ++p) {
      va[p] = *(const f32x4*)(hA  + (size_t)p * 32 * DDIM);
      v0[p] = *(const f32x4*)(hW0 + (size_t)p * 32 * DDIM);
      v1[p] = *(const f32x4*)(hW1 + (size_t)p * 32 * DDIM);
    }
    hA += BKd; hW0 += BKd; hW1 += BKd;
    __syncthreads();
#pragma unroll
    for (int p = 0; p < 2; ++p) {
      int r = srow + 32 * p;
      *(f32x4*)(&As [r * LDW + scol4]) = va[p];
      *(f32x4*)(&W0s[r * LDW + scol4]) = v0[p];
      *(f32x4*)(&W1s[r * LDW + scol4]) = v1[p];
    }
    __syncthreads();

    bf16x8 af[4];
#pragma unroll
    for (int m = 0; m < 4; ++m) {
      const float* ap = &As[(m * 16 + fr) * LDW + g * 8];
      af[m] = cvt_bf16x8(*(const f32x4*)ap, *(const f32x4*)(ap + 4));
    }
    const float* b0p = &W0s[(w * 16 + fr) * LDW + g * 8];
    const float* b1p = &W1s[(w * 16 + fr) * LDW + g * 8];
    bf16x8 bf0 = cvt_bf16x8(*(const f32x4*)b0p, *(const f32x4*)(b0p + 4));
    bf16x8 bf1 = cvt_bf16x8(*(const f32x4*)b1p, *(const f32x4*)(b1p + 4));
#pragma unroll
    for (int m = 0; m < 4; ++m) {
      acc0[m] = __builtin_amdgcn_mfma_f32_16x16x32_bf16(af[m], bf0, acc0[m], 0, 0, 0);
      acc1[m] = __builtin_amdgcn_mfma_f32_16x16x32_bf16(af[m], bf1, acc1[m], 0, 0, 0);
    }
  }

  const int col = colBase + w * 16 + fr;
  const float bz0 = B0[col];
  const float bz1 = B1[col];
#pragma unroll
  for (int m = 0; m < 4; ++m)
#pragma unroll
    for (int j = 0; j < 4; ++j) {
      int row = rowBase + m * 16 + (g << 2) + j;
      int t = TYP[row];
      OUT[(size_t)row * DDIM + col] = (t == 0) ? (acc0[m][j] + bz0) : (acc1[m][j] + bz1);
    }
}

extern "C" void kernel_launch(void* const* d_in, const int* in_sizes, int n_in,
                              void* d_out, int out_size, void* d_ws, size_t ws_size,
                              hipStream_t stream) {
  const float* H   = (const float*)d_in[0];
  const int*   TYP = (const int*)  d_in[1];
  const float* W0  = (const float*)d_in[2];
  const float* B0v = (const float*)d_in[3];
  const float* W1  = (const float*)d_in[4];
  const float* B1v = (const float*)d_in[5];
  float* OUT = (float*)d_out;

  if (ws_size < WS_NEED) {
    dim3 grid(DDIM / BNd, T_TOK / BMd);
    mot_mfma_diag<<<grid, dim3(256), 0, stream>>>(H, TYP, W0, B0v, W1, B1v, OUT);
    return;
  }

  unsigned short* Hbf  = (unsigned short*)((char*)d_ws + WS_HBF);
  unsigned short* W0bf = (unsigned short*)((char*)d_ws + WS_W0BF);
  unsigned short* W1bf = (unsigned short*)((char*)d_ws + WS_W1BF);
  int* meta = (int*)((char*)d_ws + WS_META);
  int* idx  = (int*)((char*)d_ws + WS_IDX);

  k_convert<<<2048, 256, 0, stream>>>(H,  Hbf,  T_TOK * DDIM / 4);
  k_convert<<<512,  256, 0, stream>>>(W0, W0bf, DDIM * DDIM / 4);
  k_convert<<<512,  256, 0, stream>>>(W1, W1bf, DDIM * DDIM / 4);
  k_init   <<<66,   256, 0, stream>>>(meta, idx, T_TOK + 256);
  k_count  <<<64,   256, 0, stream>>>(TYP, meta);
  k_scatter<<<64,   256, 0, stream>>>(TYP, meta, idx);
  k_gemm256<<<MT * NTILE, 512, 0, stream>>>(Hbf, W0bf, W1bf, B0v, B1v, meta, idx, OUT);
}

// Round 9
// 238.030 us; speedup vs baseline: 1.1261x; 1.1261x over previous
//
#include <hip/hip_runtime.h>
#include <hip/hip_bf16.h>
#include <stdint.h>

// MoTEmbed: out[t,:] = W_{type(t)} @ h[t,:] + b_{type(t)}
// B=4, S=4096 -> T=16384 tokens, D=2048. fp32 in/out, bf16 MFMA compute.
// Round 9: revert to R7's verified 8-phase K-loop (R8's coarse loop regressed,
// matching guide m196). New: gap-free token sort -> exactly 64 M-tiles
// (grid 512 = 2 clean block-rounds, kills the 60us third-round tail); the
// one straddling tile runs the identical pipeline twice (once per expert)
// with per-row output predicate. Prep merged into 2 kernels + memset.

#define T_TOK 16384
#define DDIM  2048
#define NT_K  32           // K tiles of 64
#define MT    64           // M tiles of 256 (gap-free sort)
#define NTILE 8            // N tiles of 256

typedef __attribute__((ext_vector_type(4))) float          f32x4;
typedef __attribute__((ext_vector_type(8))) short          bf16x8;
typedef __attribute__((ext_vector_type(2))) unsigned int   u32x2;

// ---- ws layout (bytes) ----
#define WS_HBF   0ull
#define WS_W0BF  67108864ull                 // 16384*2048*2
#define WS_W1BF  75497472ull                 // + 2048*2048*2
#define WS_META  83886080ull                 // + 2048*2048*2
#define WS_IDX   83886208ull
#define WS_NEED  (WS_IDX + 65536ull)
// meta: [0]=c0 [1]=unused [2]=cur0 [3]=cur1

__device__ __forceinline__ unsigned short cvt1_bf16(float f) {
  unsigned u = __builtin_bit_cast(unsigned, f);
  unsigned rnd = 0x7fffu + ((u >> 16) & 1u);
  return (unsigned short)((u + rnd) >> 16);
}

__device__ __forceinline__ void gload_lds16(const void* g, void* l) {
  __builtin_amdgcn_global_load_lds(
      (const __attribute__((address_space(1))) unsigned int*)g,
      (__attribute__((address_space(3))) unsigned int*)l, 16, 0, 0);
}

#define BAR()    asm volatile("s_barrier" ::: "memory")
#define VMCNT4() asm volatile("s_waitcnt vmcnt(4)" ::: "memory")
#define VMCNT0() asm volatile("s_waitcnt vmcnt(0)" ::: "memory")
#define LGKM0()  asm volatile("s_waitcnt lgkmcnt(0)" ::: "memory")

// ---------- prep: fused convert(H,W0,W1)+count ----------
__global__ void k_prep(const float* __restrict__ H, const float* __restrict__ W0,
                       const float* __restrict__ W1, const int* __restrict__ typ,
                       unsigned short* __restrict__ Hbf,
                       unsigned short* __restrict__ W0bf,
                       unsigned short* __restrict__ W1bf,
                       int* __restrict__ meta) {
  const int gid = blockIdx.x * blockDim.x + threadIdx.x;
  if (gid < T_TOK && typ[gid] == 0) atomicAdd(&meta[0], 1);
  const int nH = T_TOK * DDIM / 4;
  const int nW = DDIM * DDIM / 4;
  const int total = nH + 2 * nW;
  const int stride = gridDim.x * blockDim.x;
  for (int i = gid; i < total; i += stride) {
    const float* s; unsigned short* d; int j;
    if (i < nH)           { s = H;  d = Hbf;  j = i; }
    else if (i < nH + nW) { s = W0; d = W0bf; j = i - nH; }
    else                  { s = W1; d = W1bf; j = i - nH - nW; }
    f32x4 v = ((const f32x4*)s)[j];
    unsigned p0 = (unsigned)cvt1_bf16(v[0]) | ((unsigned)cvt1_bf16(v[1]) << 16);
    unsigned p1 = (unsigned)cvt1_bf16(v[2]) | ((unsigned)cvt1_bf16(v[3]) << 16);
    u32x2 o; o[0] = p0; o[1] = p1;
    ((u32x2*)d)[j] = o;
  }
}

__global__ void k_scatter(const int* __restrict__ typ, int* __restrict__ meta,
                          int* __restrict__ idx) {
  int i = blockIdx.x * blockDim.x + threadIdx.x;
  if (i >= T_TOK) return;
  int c0 = meta[0];                    // final (k_prep completed)
  int t = typ[i];
  int pos = (t == 0) ? atomicAdd(&meta[2], 1) : c0 + atomicAdd(&meta[3], 1);
  idx[pos] = i;
}

// ---------- 256x256 8-phase GEMM (R7-verified loop), gap-free sort ----------
// LDS: A[2 buf][2 kh][256 rows][64 B] = 64KB, then B same = 64KB.
// Swizzle (R7, conflicts == 0): data (row, slot s) at slot s ^ ((row>>1)&3);
// write via pre-swizzled global source slot cs = (lane&3) ^ ((lane>>3)&3);
// read slot = g ^ ((fr>>1)&3).
// Straddle tile (start < c0 < start+256, <=1 M-tile): run the whole pipeline
// once per expert; epilogue writes only rows with (p>=c0)==e. Pass boundary
// drains stale stages with vmcnt(0)+BAR (in-loop ledger unchanged).
__global__ __launch_bounds__(512, 2) void k_gemm256(
    const unsigned short* __restrict__ Hbf,
    const unsigned short* __restrict__ W0bf,
    const unsigned short* __restrict__ W1bf,
    const float* __restrict__ B0, const float* __restrict__ B1,
    const int* __restrict__ meta, const int* __restrict__ idx,
    float* __restrict__ OUT)
{
  __shared__ char lds[131072];

  // bijective XCD swizzle: nwg=512, 512%8==0, chunk=64
  const int orig = blockIdx.x;
  const int wg = (orig & 7) * 64 + (orig >> 3);
  const int my = wg >> 3;              // 0..63
  const int bx = wg & 7;               // 0..7

  const int tid  = threadIdx.x;
  const int lane = tid & 63;
  const int wid  = tid >> 6;           // 0..7
  const int wr   = wid >> 2;           // 0..1 (M half)
  const int wc   = wid & 3;            // 0..3 (N quarter)
  const int fr   = lane & 15;
  const int g    = lane >> 4;

  const int start = my * 256;
  const int c0    = meta[0];
  const int e0    = (start >= c0) ? 1 : 0;
  const int e1    = (start < c0 && c0 < start + 256) ? 1 : e0;
  const int colBase = bx * 256;

  // staging sources; pre-swizzled global slot (linear LDS dest)
  const int cs = (lane & 3) ^ ((lane >> 3) & 3);
  const char* aS[2];
  int rt[2];
#pragma unroll
  for (int l = 0; l < 2; ++l) {
    int ch = 2 * wid + l;
    rt[l] = ch * 16 + (lane >> 2);
    int orow = idx[start + rt[l]];
    aS[l] = (const char*)Hbf + (size_t)orow * 4096 + cs * 16;
  }
  const int chB = (2 * wid) * 1024;    // wave-uniform chunk base in a section

  // fragment byte offsets within a kh-section (swizzled slot)
  const int sw = (g ^ ((fr >> 1) & 3)) << 4;
  int aF[8], bF[4];
#pragma unroll
  for (int m = 0; m < 8; ++m) aF[m] = ((wr * 128 + m * 16 + fr) << 6) + sw;
#pragma unroll
  for (int n = 0; n < 4; ++n) bF[n] = ((wc * 64 + n * 16 + fr) << 6) + sw;

  for (int e = e0; e <= e1; ++e) {
    const unsigned short* Wb = e ? W1bf : W0bf;
    const char* wS[2];
#pragma unroll
    for (int l = 0; l < 2; ++l)
      wS[l] = (const char*)(Wb + (size_t)(colBase + rt[l]) * DDIM) + cs * 16;

    f32x4 acc[8][4];
#pragma unroll
    for (int m = 0; m < 8; ++m)
#pragma unroll
      for (int n = 0; n < 4; ++n) acc[m][n] = (f32x4)0.0f;

    auto STAGE_A = [&](int d, int kh, int tn) {
      char* dst = lds + (d << 15) + (kh << 14) + chB;
      int ko = tn * 128 + kh * 64;
      gload_lds16(aS[0] + ko, dst);
      gload_lds16(aS[1] + ko, dst + 1024);
    };
    auto STAGE_B = [&](int d, int kh, int tn) {
      char* dst = lds + 65536 + (d << 15) + (kh << 14) + chB;
      int ko = tn * 128 + kh * 64;
      gload_lds16(wS[0] + ko, dst);
      gload_lds16(wS[1] + ko, dst + 1024);
    };

    // pass boundary: drain any stale stages before re-staging buffers
    VMCNT0();
    BAR();

    // prologue: tile 0 -> buf 0; kh0 landed at barrier (census: 8, vmcnt4)
    STAGE_A(0, 0, 0); STAGE_B(0, 0, 0); STAGE_A(0, 1, 0); STAGE_B(0, 1, 0);
    VMCNT4();
    BAR();

#pragma unroll 2
    for (int t = 0; t < NT_K; ++t) {
      const int c = t & 1, d = c ^ 1;
      int tn = t + 1; if (tn == NT_K) tn = NT_K - 1; // clamp keeps census exact
      const char* Ak0 = lds + (c << 15);
      const char* Ak1 = Ak0 + 16384;
      const char* Bk0 = lds + 65536 + (c << 15);
      const char* Bk1 = Bk0 + 16384;

      bf16x8 a[8], b0v, b1v, b2v, b3v;

      // ---- P1: kh0 x n{0,1} ----
#pragma unroll
      for (int m = 0; m < 8; ++m) a[m] = *(const bf16x8*)(Ak0 + aF[m]);
      b0v = *(const bf16x8*)(Bk0 + bF[0]);
      b1v = *(const bf16x8*)(Bk0 + bF[1]);
      STAGE_A(d, 0, tn);
      BAR(); LGKM0();
      __builtin_amdgcn_s_setprio(1);
#pragma unroll
      for (int m = 0; m < 8; ++m) {
        acc[m][0] = __builtin_amdgcn_mfma_f32_16x16x32_bf16(a[m], b0v, acc[m][0], 0, 0, 0);
        acc[m][1] = __builtin_amdgcn_mfma_f32_16x16x32_bf16(a[m], b1v, acc[m][1], 0, 0, 0);
      }
      __builtin_amdgcn_s_setprio(0);
      BAR();

      // ---- P2: kh0 x n{2,3} (a reused) ----
      b2v = *(const bf16x8*)(Bk0 + bF[2]);
      b3v = *(const bf16x8*)(Bk0 + bF[3]);
      STAGE_B(d, 0, tn);
      VMCNT4();                        // drains prev-tile kh1 stages (P3 reads)
      BAR(); LGKM0();
      __builtin_amdgcn_s_setprio(1);
#pragma unroll
      for (int m = 0; m < 8; ++m) {
        acc[m][2] = __builtin_amdgcn_mfma_f32_16x16x32_bf16(a[m], b2v, acc[m][2], 0, 0, 0);
        acc[m][3] = __builtin_amdgcn_mfma_f32_16x16x32_bf16(a[m], b3v, acc[m][3], 0, 0, 0);
      }
      __builtin_amdgcn_s_setprio(0);
      BAR();

      // ---- P3: kh1 x n{0,1} ----
#pragma unroll
      for (int m = 0; m < 8; ++m) a[m] = *(const bf16x8*)(Ak1 + aF[m]);
      b0v = *(const bf16x8*)(Bk1 + bF[0]);
      b1v = *(const bf16x8*)(Bk1 + bF[1]);
      STAGE_A(d, 1, tn);
      BAR(); LGKM0();
      __builtin_amdgcn_s_setprio(1);
#pragma unroll
      for (int m = 0; m < 8; ++m) {
        acc[m][0] = __builtin_amdgcn_mfma_f32_16x16x32_bf16(a[m], b0v, acc[m][0], 0, 0, 0);
        acc[m][1] = __builtin_amdgcn_mfma_f32_16x16x32_bf16(a[m], b1v, acc[m][1], 0, 0, 0);
      }
      __builtin_amdgcn_s_setprio(0);
      BAR();

      // ---- P4: kh1 x n{2,3} ----
      b2v = *(const bf16x8*)(Bk1 + bF[2]);
      b3v = *(const bf16x8*)(Bk1 + bF[3]);
      STAGE_B(d, 1, tn);
      VMCNT4();                        // drains this tile's kh0 stages (next P1)
      BAR(); LGKM0();
      __builtin_amdgcn_s_setprio(1);
#pragma unroll
      for (int m = 0; m < 8; ++m) {
        acc[m][2] = __builtin_amdgcn_mfma_f32_16x16x32_bf16(a[m], b2v, acc[m][2], 0, 0, 0);
        acc[m][3] = __builtin_amdgcn_mfma_f32_16x16x32_bf16(a[m], b3v, acc[m][3], 0, 0, 0);
      }
      __builtin_amdgcn_s_setprio(0);
      BAR();
    }

    // ---- epilogue: bias + per-row expert predicate + scatter ----
    const float* Bv = e ? B1 : B0;
    float bias[4];
    int cols[4];
#pragma unroll
    for (int n = 0; n < 4; ++n) {
      cols[n] = colBase + wc * 64 + n * 16 + fr;
      bias[n] = Bv[cols[n]];
    }
#pragma unroll
    for (int m = 0; m < 8; ++m) {
      int lb = wr * 128 + m * 16 + (g << 2);
#pragma unroll
      for (int j = 0; j < 4; ++j) {
        int p = start + lb + j;
        if (((p >= c0) ? 1 : 0) != e) continue;
        int orow = idx[p];
        float* op = OUT + (size_t)orow * DDIM;
#pragma unroll
        for (int n = 0; n < 4; ++n) op[cols[n]] = acc[m][n][j] + bias[n];
      }
    }
  }
}

// ---------- fallback: verified round-4 kernel ----------
#define BMd 64
#define BNd 64
#define BKd 32
#define LDW 36

__device__ __forceinline__ bf16x8 cvt_bf16x8(f32x4 lo, f32x4 hi) {
  bf16x8 r;
#pragma unroll
  for (int i = 0; i < 4; ++i) {
    r[i]     = (short)cvt1_bf16(lo[i]);
    r[i + 4] = (short)cvt1_bf16(hi[i]);
  }
  return r;
}

__global__ __launch_bounds__(256, 2) void mot_mfma_diag(
    const float* __restrict__ H,  const int* __restrict__ TYP,
    const float* __restrict__ W0, const float* __restrict__ B0,
    const float* __restrict__ W1, const float* __restrict__ B1,
    float* __restrict__ OUT)
{
  __shared__ float As[BMd * LDW];
  __shared__ float W0s[BNd * LDW];
  __shared__ float W1s[BNd * LDW];

  const int tid = threadIdx.x;
  const int rowBase = blockIdx.y * BMd;
  const int colBase = blockIdx.x * BNd;
  const int srow  = tid >> 3;
  const int scol4 = (tid & 7) << 2;
  const float* hA  = H  + (size_t)(rowBase + srow) * DDIM + scol4;
  const float* hW0 = W0 + (size_t)(colBase + srow) * DDIM + scol4;
  const float* hW1 = W1 + (size_t)(colBase + srow) * DDIM + scol4;

  const int lane = tid & 63;
  const int w    = tid >> 6;
  const int fr   = lane & 15;
  const int g    = lane >> 4;

  f32x4 acc0[4], acc1[4];
#pragma unroll
  for (int m = 0; m < 4; ++m) { acc0[m] = (f32x4)0.0f; acc1[m] = (f32x4)0.0f; }

  for (int k0 = 0; k0 < DDIM; k0 += BKd) {
    f32x4 va[2], v0[2], v1[2];
#pragma unroll
    for (int p = 0; p < 2; ++p) {
      va[p] = *(const f32x4*)(hA  + (size_t)p * 32 * DDIM);
      v0[p] = *(const f32x4*)(hW0 + (size_t)p * 32 * DDIM);
      v1[p] = *(const f32x4*)(hW1 + (size_t)p * 32 * DDIM);
    }
    hA += BKd; hW0 += BKd; hW1 += BKd;
    __syncthreads();
#pragma unroll
    for (int p = 0; p < 2; ++p) {
      int r = srow + 32 * p;
      *(f32x4*)(&As [r * LDW + scol4]) = va[p];
      *(f32x4*)(&W0s[r * LDW + scol4]) = v0[p];
      *(f32x4*)(&W1s[r * LDW + scol4]) = v1[p];
    }
    __syncthreads();

    bf16x8 af[4];
#pragma unroll
    for (int m = 0; m < 4; ++m) {
      const float* ap = &As[(m * 16 + fr) * LDW + g * 8];
      af[m] = cvt_bf16x8(*(const f32x4*)ap, *(const f32x4*)(ap + 4));
    }
    const float* b0p = &W0s[(w * 16 + fr) * LDW + g * 8];
    const float* b1p = &W1s[(w * 16 + fr) * LDW + g * 8];
    bf16x8 bf0 = cvt_bf16x8(*(const f32x4*)b0p, *(const f32x4*)(b0p + 4));
    bf16x8 bf1 = cvt_bf16x8(*(const f32x4*)b1p, *(const f32x4*)(b1p + 4));
#pragma unroll
    for (int m = 0; m < 4; ++m) {
      acc0[m] = __builtin_amdgcn_mfma_f32_16x16x32_bf16(af[m], bf0, acc0[m], 0, 0, 0);
      acc1[m] = __builtin_amdgcn_mfma_f32_16x16x32_bf16(af[m], bf1, acc1[m], 0, 0, 0);
    }
  }

  const int col = colBase + w * 16 + fr;
  const float bz0 = B0[col];
  const float bz1 = B1[col];
#pragma unroll
  for (int m = 0; m < 4; ++m)
#pragma unroll
    for (int j = 0; j < 4; ++j) {
      int row = rowBase + m * 16 + (g << 2) + j;
      int t = TYP[row];
      OUT[(size_t)row * DDIM + col] = (t == 0) ? (acc0[m][j] + bz0) : (acc1[m][j] + bz1);
    }
}

extern "C" void kernel_launch(void* const* d_in, const int* in_sizes, int n_in,
                              void* d_out, int out_size, void* d_ws, size_t ws_size,
                              hipStream_t stream) {
  const float* H   = (const float*)d_in[0];
  const int*   TYP = (const int*)  d_in[1];
  const float* W0  = (const float*)d_in[2];
  const float* B0v = (const float*)d_in[3];
  const float* W1  = (const float*)d_in[4];
  const float* B1v = (const float*)d_in[5];
  float* OUT = (float*)d_out;

  if (ws_size < WS_NEED) {
    dim3 grid(DDIM / BNd, T_TOK / BMd);
    mot_mfma_diag<<<grid, dim3(256), 0, stream>>>(H, TYP, W0, B0v, W1, B1v, OUT);
    return;
  }

  unsigned short* Hbf  = (unsigned short*)((char*)d_ws + WS_HBF);
  unsigned short* W0bf = (unsigned short*)((char*)d_ws + WS_W0BF);
  unsigned short* W1bf = (unsigned short*)((char*)d_ws + WS_W1BF);
  int* meta = (int*)((char*)d_ws + WS_META);
  int* idx  = (int*)((char*)d_ws + WS_IDX);

  hipMemsetAsync(meta, 0, 16, stream);
  k_prep   <<<4096, 256, 0, stream>>>(H, W0, W1, TYP, Hbf, W0bf, W1bf, meta);
  k_scatter<<<64,   256, 0, stream>>>(TYP, meta, idx);
  k_gemm256<<<MT * NTILE, 512, 0, stream>>>(Hbf, W0bf, W1bf, B0v, B1v, meta, idx, OUT);
}

// Round 10
// 237.977 us; speedup vs baseline: 1.1263x; 1.0002x over previous
//
#include <hip/hip_runtime.h>
#include <hip/hip_bf16.h>
#include <stdint.h>

// MoTEmbed: out[t,:] = W_{type(t)} @ h[t,:] + b_{type(t)}
// B=4, S=4096 -> T=16384 tokens, D=2048. fp32 in/out, bf16 MFMA compute.
// Round 10: deep-prefetch 4-phase K-loop. Stages issued 5-7 phases ahead of
// consumption -> vmcnt(10) drains are pre-satisfied (T4 done right). Reads
// balanced 8/4/8/4 via m-half phase split. Straddle M-tile swapped to my=0
// (earliest dispatch). Sort/swizzle/fragment maps identical to verified R7/R9.

#define T_TOK 16384
#define DDIM  2048
#define NT_K  32           // K tiles of 64
#define MT    64           // M tiles of 256 (gap-free sort)
#define NTILE 8            // N tiles of 256

typedef __attribute__((ext_vector_type(4))) float          f32x4;
typedef __attribute__((ext_vector_type(8))) short          bf16x8;
typedef __attribute__((ext_vector_type(2))) unsigned int   u32x2;

// ---- ws layout (bytes) ----
#define WS_HBF   0ull
#define WS_W0BF  67108864ull                 // 16384*2048*2
#define WS_W1BF  75497472ull                 // + 2048*2048*2
#define WS_META  83886080ull                 // + 2048*2048*2
#define WS_IDX   83886208ull
#define WS_NEED  (WS_IDX + 65536ull)
// meta: [0]=c0 [1]=unused [2]=cur0 [3]=cur1

__device__ __forceinline__ unsigned short cvt1_bf16(float f) {
  unsigned u = __builtin_bit_cast(unsigned, f);
  unsigned rnd = 0x7fffu + ((u >> 16) & 1u);
  return (unsigned short)((u + rnd) >> 16);
}

__device__ __forceinline__ void gload_lds16(const void* g, void* l) {
  __builtin_amdgcn_global_load_lds(
      (const __attribute__((address_space(1))) unsigned int*)g,
      (__attribute__((address_space(3))) unsigned int*)l, 16, 0, 0);
}

#define BAR()     asm volatile("s_barrier" ::: "memory")
#define VMCNT10() asm volatile("s_waitcnt vmcnt(10)" ::: "memory")
#define VMCNT0()  asm volatile("s_waitcnt vmcnt(0)" ::: "memory")
#define LGKM0()   asm volatile("s_waitcnt lgkmcnt(0)" ::: "memory")

// ---------- prep: fused convert(H,W0,W1)+count ----------
__global__ void k_prep(const float* __restrict__ H, const float* __restrict__ W0,
                       const float* __restrict__ W1, const int* __restrict__ typ,
                       unsigned short* __restrict__ Hbf,
                       unsigned short* __restrict__ W0bf,
                       unsigned short* __restrict__ W1bf,
                       int* __restrict__ meta) {
  const int gid = blockIdx.x * blockDim.x + threadIdx.x;
  if (gid < T_TOK && typ[gid] == 0) atomicAdd(&meta[0], 1);
  const int nH = T_TOK * DDIM / 4;
  const int nW = DDIM * DDIM / 4;
  const int total = nH + 2 * nW;
  const int stride = gridDim.x * blockDim.x;
  for (int i = gid; i < total; i += stride) {
    const float* s; unsigned short* d; int j;
    if (i < nH)           { s = H;  d = Hbf;  j = i; }
    else if (i < nH + nW) { s = W0; d = W0bf; j = i - nH; }
    else                  { s = W1; d = W1bf; j = i - nH - nW; }
    f32x4 v = ((const f32x4*)s)[j];
    unsigned p0 = (unsigned)cvt1_bf16(v[0]) | ((unsigned)cvt1_bf16(v[1]) << 16);
    unsigned p1 = (unsigned)cvt1_bf16(v[2]) | ((unsigned)cvt1_bf16(v[3]) << 16);
    u32x2 o; o[0] = p0; o[1] = p1;
    ((u32x2*)d)[j] = o;
  }
}

__global__ void k_scatter(const int* __restrict__ typ, int* __restrict__ meta,
                          int* __restrict__ idx) {
  int i = blockIdx.x * blockDim.x + threadIdx.x;
  if (i >= T_TOK) return;
  int c0 = meta[0];                    // final (k_prep completed)
  int t = typ[i];
  int pos = (t == 0) ? atomicAdd(&meta[2], 1) : c0 + atomicAdd(&meta[3], 1);
  idx[pos] = i;
}

// ---------- 256x256 deep-prefetch GEMM ----------
// LDS: A[2 buf][2 kh][256 rows][64 B] = 64KB, then B same = 64KB.
// Swizzle (R7-verified, conflicts==0): data (row, slot s) at slot
// s ^ ((row>>1)&3); write via pre-swizzled global source slot
// cs = (lane&3) ^ ((lane>>3)&3); read slot = g ^ ((fr>>1)&3).
// Stage schedule (deep): P1(t): A1(t+1)->buf d; P2(t): B0(t+2)->buf c;
// P3(t): A0(t+2)->buf c; P4(t): B1(t+2)->buf c. Each overwrite target's
// last reader is certified by an interposed barrier (B0(t) read P1 only,
// A0(t) P1+P2, B1(t) P3, A1(t) P3+P4). FIFO drains: vmcnt(10) at end-P2
// (certifies A1(t),B1(t) for P3) and end-P4 (certifies A0(t+1),B0(t+1)
// for next P1); drained loads are 5-7 phases old -> pre-satisfied.
// Prologue: [B0(0),A0(0),B1(0),A1(0),B0(1),A0(1),B1(1)] + vmcnt(10).
__global__ __launch_bounds__(512, 2) void k_gemm256(
    const unsigned short* __restrict__ Hbf,
    const unsigned short* __restrict__ W0bf,
    const unsigned short* __restrict__ W1bf,
    const float* __restrict__ B0, const float* __restrict__ B1,
    const int* __restrict__ meta, const int* __restrict__ idx,
    float* __restrict__ OUT)
{
  __shared__ char lds[131072];

  // bijective XCD swizzle: nwg=512, 512%8==0, chunk=64
  const int orig = blockIdx.x;
  const int wg = (orig & 7) * 64 + (orig >> 3);
  int my = wg >> 3;                    // 0..63
  const int bx = wg & 7;               // 0..7

  const int c0 = meta[0];
  int ms = c0 >> 8; if (ms > MT - 1) ms = MT - 1;
  // straddle tile first (earliest dispatch): swap my 0 <-> ms
  my = (my == 0) ? ms : (my == ms) ? 0 : my;

  const int tid  = threadIdx.x;
  const int lane = tid & 63;
  const int wid  = tid >> 6;           // 0..7
  const int wr   = wid >> 2;           // 0..1 (M half)
  const int wc   = wid & 3;            // 0..3 (N quarter)
  const int fr   = lane & 15;
  const int g    = lane >> 4;

  const int start = my * 256;
  const int e0    = (start >= c0) ? 1 : 0;
  const int e1    = (start < c0 && c0 < start + 256) ? 1 : e0;
  const int colBase = bx * 256;

  // staging sources; pre-swizzled global slot (linear LDS dest)
  const int cs = (lane & 3) ^ ((lane >> 3) & 3);
  const char* aS[2];
  int rt[2];
#pragma unroll
  for (int l = 0; l < 2; ++l) {
    int ch = 2 * wid + l;
    rt[l] = ch * 16 + (lane >> 2);
    int orow = idx[start + rt[l]];
    aS[l] = (const char*)Hbf + (size_t)orow * 4096 + cs * 16;
  }
  const int chB = (2 * wid) * 1024;    // wave-uniform chunk base in a section

  // fragment byte offsets within a kh-section (swizzled slot)
  const int sw = (g ^ ((fr >> 1) & 3)) << 4;
  int aF[8], bF[4];
#pragma unroll
  for (int m = 0; m < 8; ++m) aF[m] = ((wr * 128 + m * 16 + fr) << 6) + sw;
#pragma unroll
  for (int n = 0; n < 4; ++n) bF[n] = ((wc * 64 + n * 16 + fr) << 6) + sw;

  for (int e = e0; e <= e1; ++e) {
    const unsigned short* Wb = e ? W1bf : W0bf;
    const char* wS[2];
#pragma unroll
    for (int l = 0; l < 2; ++l)
      wS[l] = (const char*)(Wb + (size_t)(colBase + rt[l]) * DDIM) + cs * 16;

    f32x4 acc[8][4];
#pragma unroll
    for (int m = 0; m < 8; ++m)
#pragma unroll
      for (int n = 0; n < 4; ++n) acc[m][n] = (f32x4)0.0f;

    auto STAGE_A = [&](int d, int kh, int tn) {
      char* dst = lds + (d << 15) + (kh << 14) + chB;
      int ko = tn * 128 + kh * 64;
      gload_lds16(aS[0] + ko, dst);
      gload_lds16(aS[1] + ko, dst + 1024);
    };
    auto STAGE_B = [&](int d, int kh, int tn) {
      char* dst = lds + 65536 + (d << 15) + (kh << 14) + chB;
      int ko = tn * 128 + kh * 64;
      gload_lds16(wS[0] + ko, dst);
      gload_lds16(wS[1] + ko, dst + 1024);
    };

    // pass boundary: drain any stale stages before re-staging buffers
    VMCNT0();
    BAR();

    // prologue (FIFO order matters for drain census):
    STAGE_B(0, 0, 0); STAGE_A(0, 0, 0);   // B0(0), A0(0)
    STAGE_B(0, 1, 0); STAGE_A(0, 1, 0);   // B1(0), A1(0)
    STAGE_B(1, 0, 1); STAGE_A(1, 0, 1);   // B0(1), A0(1)
    STAGE_B(1, 1, 1);                     // B1(1)   [A1(1) staged at P1(0)]
    VMCNT10();                            // certifies B0(0), A0(0)
    BAR();

#pragma unroll 2
    for (int t = 0; t < NT_K; ++t) {
      const int c = t & 1, d = c ^ 1;
      int t1 = t + 1; if (t1 >= NT_K) t1 = NT_K - 1;
      int t2 = t + 2; if (t2 >= NT_K) t2 = NT_K - 1;
      const char* Ak0 = lds + (c << 15);
      const char* Ak1 = Ak0 + 16384;
      const char* Bk0 = lds + 65536 + (c << 15);
      const char* Bk1 = Bk0 + 16384;

      bf16x8 a[4], b[4];

      // ---- P1: kh0, m0-3 (8 reads) ----
#pragma unroll
      for (int m = 0; m < 4; ++m) a[m] = *(const bf16x8*)(Ak0 + aF[m]);
#pragma unroll
      for (int n = 0; n < 4; ++n) b[n] = *(const bf16x8*)(Bk0 + bF[n]);
      STAGE_A(d, 1, t1);                 // A1(t+1)
      BAR(); LGKM0();
      __builtin_amdgcn_s_setprio(1);
#pragma unroll
      for (int n = 0; n < 4; ++n)
#pragma unroll
        for (int m = 0; m < 4; ++m)
          acc[m][n] = __builtin_amdgcn_mfma_f32_16x16x32_bf16(a[m], b[n], acc[m][n], 0, 0, 0);
      __builtin_amdgcn_s_setprio(0);
      BAR();

      // ---- P2: kh0, m4-7 (4 reads, b reused) ----
#pragma unroll
      for (int m = 0; m < 4; ++m) a[m] = *(const bf16x8*)(Ak0 + aF[m + 4]);
      STAGE_B(c, 0, t2);                 // B0(t+2) (B0(t) read-certified at P1 BAR)
      VMCNT10();                         // certifies A1(t), B1(t) for P3
      BAR(); LGKM0();
      __builtin_amdgcn_s_setprio(1);
#pragma unroll
      for (int n = 0; n < 4; ++n)
#pragma unroll
        for (int m = 0; m < 4; ++m)
          acc[m + 4][n] = __builtin_amdgcn_mfma_f32_16x16x32_bf16(a[m], b[n], acc[m + 4][n], 0, 0, 0);
      __builtin_amdgcn_s_setprio(0);
      BAR();

      // ---- P3: kh1, m0-3 (8 reads) ----
#pragma unroll
      for (int m = 0; m < 4; ++m) a[m] = *(const bf16x8*)(Ak1 + aF[m]);
#pragma unroll
      for (int n = 0; n < 4; ++n) b[n] = *(const bf16x8*)(Bk1 + bF[n]);
      STAGE_A(c, 0, t2);                 // A0(t+2) (A0(t) certified at P2 BAR)
      BAR(); LGKM0();
      __builtin_amdgcn_s_setprio(1);
#pragma unroll
      for (int n = 0; n < 4; ++n)
#pragma unroll
        for (int m = 0; m < 4; ++m)
          acc[m][n] = __builtin_amdgcn_mfma_f32_16x16x32_bf16(a[m], b[n], acc[m][n], 0, 0, 0);
      __builtin_amdgcn_s_setprio(0);
      BAR();

      // ---- P4: kh1, m4-7 (4 reads, b reused) ----
#pragma unroll
      for (int m = 0; m < 4; ++m) a[m] = *(const bf16x8*)(Ak1 + aF[m + 4]);
      STAGE_B(c, 1, t2);                 // B1(t+2) (B1(t) certified at P3 BAR)
      VMCNT10();                         // certifies A0(t+1), B0(t+1) for next P1
      BAR(); LGKM0();
      __builtin_amdgcn_s_setprio(1);
#pragma unroll
      for (int n = 0; n < 4; ++n)
#pragma unroll
        for (int m = 0; m < 4; ++m)
          acc[m + 4][n] = __builtin_amdgcn_mfma_f32_16x16x32_bf16(a[m], b[n], acc[m + 4][n], 0, 0, 0);
      __builtin_amdgcn_s_setprio(0);
      BAR();
    }

    // ---- epilogue: bias + per-row expert predicate + scatter ----
    const float* Bv = e ? B1 : B0;
    float bias[4];
    int cols[4];
#pragma unroll
    for (int n = 0; n < 4; ++n) {
      cols[n] = colBase + wc * 64 + n * 16 + fr;
      bias[n] = Bv[cols[n]];
    }
#pragma unroll
    for (int m = 0; m < 8; ++m) {
      int lb = wr * 128 + m * 16 + (g << 2);
#pragma unroll
      for (int j = 0; j < 4; ++j) {
        int p = start + lb + j;
        if (((p >= c0) ? 1 : 0) != e) continue;
        int orow = idx[p];
        float* op = OUT + (size_t)orow * DDIM;
#pragma unroll
        for (int n = 0; n < 4; ++n) op[cols[n]] = acc[m][n][j] + bias[n];
      }
    }
  }
}

// ---------- fallback: verified round-4 kernel ----------
#define BMd 64
#define BNd 64
#define BKd 32
#define LDW 36

__device__ __forceinline__ bf16x8 cvt_bf16x8(f32x4 lo, f32x4 hi) {
  bf16x8 r;
#pragma unroll
  for (int i = 0; i < 4; ++i) {
    r[i]     = (short)cvt1_bf16(lo[i]);
    r[i + 4] = (short)cvt1_bf16(hi[i]);
  }
  return r;
}

__global__ __launch_bounds__(256, 2) void mot_mfma_diag(
    const float* __restrict__ H,  const int* __restrict__ TYP,
    const float* __restrict__ W0, const float* __restrict__ B0,
    const float* __restrict__ W1, const float* __restrict__ B1,
    float* __restrict__ OUT)
{
  __shared__ float As[BMd * LDW];
  __shared__ float W0s[BNd * LDW];
  __shared__ float W1s[BNd * LDW];

  const int tid = threadIdx.x;
  const int rowBase = blockIdx.y * BMd;
  const int colBase = blockIdx.x * BNd;
  const int srow  = tid >> 3;
  const int scol4 = (tid & 7) << 2;
  const float* hA  = H  + (size_t)(rowBase + srow) * DDIM + scol4;
  const float* hW0 = W0 + (size_t)(colBase + srow) * DDIM + scol4;
  const float* hW1 = W1 + (size_t)(colBase + srow) * DDIM + scol4;

  const int lane = tid & 63;
  const int w    = tid >> 6;
  const int fr   = lane & 15;
  const int g    = lane >> 4;

  f32x4 acc0[4], acc1[4];
#pragma unroll
  for (int m = 0; m < 4; ++m) { acc0[m] = (f32x4)0.0f; acc1[m] = (f32x4)0.0f; }

  for (int k0 = 0; k0 < DDIM; k0 += BKd) {
    f32x4 va[2], v0[2], v1[2];
#pragma unroll
    for (int p = 0; p < 2; ++p) {
      va[p] = *(const f32x4*)(hA  + (size_t)p * 32 * DDIM);
      v0[p] = *(const f32x4*)(hW0 + (size_t)p * 32 * DDIM);
      v1[p] = *(const f32x4*)(hW1 + (size_t)p * 32 * DDIM);
    }
    hA += BKd; hW0 += BKd; hW1 += BKd;
    __syncthreads();
#pragma unroll
    for (int p = 0; p < 2; ++p) {
      int r = srow + 32 * p;
      *(f32x4*)(&As [r * LDW + scol4]) = va[p];
      *(f32x4*)(&W0s[r * LDW + scol4]) = v0[p];
      *(f32x4*)(&W1s[r * LDW + scol4]) = v1[p];
    }
    __syncthreads();

    bf16x8 af[4];
#pragma unroll
    for (int m = 0; m < 4; ++m) {
      const float* ap = &As[(m * 16 + fr) * LDW + g * 8];
      af[m] = cvt_bf16x8(*(const f32x4*)ap, *(const f32x4*)(ap + 4));
    }
    const float* b0p = &W0s[(w * 16 + fr) * LDW + g * 8];
    const float* b1p = &W1s[(w * 16 + fr) * LDW + g * 8];
    bf16x8 bf0 = cvt_bf16x8(*(const f32x4*)b0p, *(const f32x4*)(b0p + 4));
    bf16x8 bf1 = cvt_bf16x8(*(const f32x4*)b1p, *(const f32x4*)(b1p + 4));
#pragma unroll
    for (int m = 0; m < 4; ++m) {
      acc0[m] = __builtin_amdgcn_mfma_f32_16x16x32_bf16(af[m], bf0, acc0[m], 0, 0, 0);
      acc1[m] = __builtin_amdgcn_mfma_f32_16x16x32_bf16(af[m], bf1, acc1[m], 0, 0, 0);
    }
  }

  const int col = colBase + w * 16 + fr;
  const float bz0 = B0[col];
  const float bz1 = B1[col];
#pragma unroll
  for (int m = 0; m < 4; ++m)
#pragma unroll
    for (int j = 0; j < 4; ++j) {
      int row = rowBase + m * 16 + (g << 2) + j;
      int t = TYP[row];
      OUT[(size_t)row * DDIM + col] = (t == 0) ? (acc0[m][j] + bz0) : (acc1[m][j] + bz1);
    }
}

extern "C" void kernel_launch(void* const* d_in, const int* in_sizes, int n_in,
                              void* d_out, int out_size, void* d_ws, size_t ws_size,
                              hipStream_t stream) {
  const float* H   = (const float*)d_in[0];
  const int*   TYP = (const int*)  d_in[1];
  const float* W0  = (const float*)d_in[2];
  const float* B0v = (const float*)d_in[3];
  const float* W1  = (const float*)d_in[4];
  const float* B1v = (const float*)d_in[5];
  float* OUT = (float*)d_out;

  if (ws_size < WS_NEED) {
    dim3 grid(DDIM / BNd, T_TOK / BMd);
    mot_mfma_diag<<<grid, dim3(256), 0, stream>>>(H, TYP, W0, B0v, W1, B1v, OUT);
    return;
  }

  unsigned short* Hbf  = (unsigned short*)((char*)d_ws + WS_HBF);
  unsigned short* W0bf = (unsigned short*)((char*)d_ws + WS_W0BF);
  unsigned short* W1bf = (unsigned short*)((char*)d_ws + WS_W1BF);
  int* meta = (int*)((char*)d_ws + WS_META);
  int* idx  = (int*)((char*)d_ws + WS_IDX);

  hipMemsetAsync(meta, 0, 16, stream);
  k_prep   <<<4096, 256, 0, stream>>>(H, W0, W1, TYP, Hbf, W0bf, W1bf, meta);
  k_scatter<<<64,   256, 0, stream>>>(TYP, meta, idx);
  k_gemm256<<<MT * NTILE, 512, 0, stream>>>(Hbf, W0bf, W1bf, B0v, B1v, meta, idx, OUT);
}